// Round 3
// baseline (112.977 us; speedup 1.0000x reference)
//
#include <hip/hip_runtime.h>

// mean(x1 @ x2^T) = dot(colsum(x1), colsum(x2)) / N^2
// 3-phase atomic-free tree.
// R1 lesson: contended fp32 atomics cost ~60us -> deterministic partials.
// R2 lesson: dur_us includes ~61-75us of harness reset work (256MiB ws
//   poison fill @41us + input restore copies); our controllable part was
//   ~26-40us because phase 1 ran at 1 block/CU (4 waves/CU) with too little
//   memory-level parallelism. R3: 4 blocks/CU.

#define N_ROWS 8192
#define D_COLS 1024
#define P_BLK 512                 // partial blocks per input (4 per CU total)
#define RPB (N_ROWS / P_BLK)      // 16 rows per block
#define P2_BLOCKS 32              // phase-2 blocks (32 columns each)

// d_ws layout: [2][P_BLK][D_COLS] float partials (4 MiB), then [P2_BLOCKS] double.

__global__ __launch_bounds__(256) void colsum_partial(
    const float* __restrict__ x1, const float* __restrict__ x2,
    float* __restrict__ part) {
  const float* x = (blockIdx.y == 0) ? x1 : x2;
  const int tid = threadIdx.x;  // owns columns [4*tid, 4*tid+4)
  const float4* xr =
      (const float4*)x + (size_t)blockIdx.x * RPB * (D_COLS / 4) + tid;
  // Two independent accumulators to expose load/add ILP.
  float4 a0 = make_float4(0.f, 0.f, 0.f, 0.f);
  float4 a1 = make_float4(0.f, 0.f, 0.f, 0.f);
#pragma unroll
  for (int r = 0; r < RPB; r += 2) {
    float4 v0 = xr[(size_t)r * (D_COLS / 4)];
    float4 v1 = xr[(size_t)(r + 1) * (D_COLS / 4)];
    a0.x += v0.x; a0.y += v0.y; a0.z += v0.z; a0.w += v0.w;
    a1.x += v1.x; a1.y += v1.y; a1.z += v1.z; a1.w += v1.w;
  }
  a0.x += a1.x; a0.y += a1.y; a0.z += a1.z; a0.w += a1.w;
  float4* dst =
      (float4*)(part + ((size_t)blockIdx.y * P_BLK + blockIdx.x) * D_COLS) + tid;
  *dst = a0;  // coalesced 4 KiB per block, no atomics
}

__global__ __launch_bounds__(256) void colreduce_dot(
    const float* __restrict__ part, double* __restrict__ bdot) {
  __shared__ double sh1[256], sh2[256];
  const int t = threadIdx.x;
  const int cl = t & 31;        // column within this block's 32-column chunk
  const int g = t >> 5;         // partial-group 0..7
  const int c = blockIdx.x * 32 + cl;
  const float* p1 = part + c;
  const float* p2 = part + (size_t)P_BLK * D_COLS + c;
  double s1 = 0.0, s2 = 0.0;
  for (int p = g; p < P_BLK; p += 8) {
    s1 += (double)p1[(size_t)p * D_COLS];
    s2 += (double)p2[(size_t)p * D_COLS];
  }
  sh1[t] = s1; sh2[t] = s2;
  __syncthreads();
  if (t < 64) {
    double prod = 0.0;
    if (t < 32) {
      double a = 0.0, b = 0.0;
#pragma unroll
      for (int gg = 0; gg < 8; ++gg) {
        a += sh1[gg * 32 + t];
        b += sh2[gg * 32 + t];
      }
      prod = a * b;  // s1[c] * s2[c]
    }
#pragma unroll
    for (int off = 32; off > 0; off >>= 1) prod += __shfl_down(prod, off, 64);
    if (t == 0) bdot[blockIdx.x] = prod;
  }
}

__global__ __launch_bounds__(64) void final_scale(
    const double* __restrict__ bdot, float* __restrict__ out) {
  const int t = threadIdx.x;
  double s = (t < P2_BLOCKS) ? bdot[t] : 0.0;
#pragma unroll
  for (int off = 32; off > 0; off >>= 1) s += __shfl_down(s, off, 64);
  if (t == 0) out[0] = (float)(s / ((double)N_ROWS * (double)N_ROWS));
}

extern "C" void kernel_launch(void* const* d_in, const int* in_sizes, int n_in,
                              void* d_out, int out_size, void* d_ws,
                              size_t ws_size, hipStream_t stream) {
  const float* x1 = (const float*)d_in[0];
  const float* x2 = (const float*)d_in[1];
  float* part = (float*)d_ws;  // 2 * 512 * 1024 floats = 4 MiB
  double* bdot =
      (double*)((char*)d_ws + (size_t)2 * P_BLK * D_COLS * sizeof(float));
  float* out = (float*)d_out;

  colsum_partial<<<dim3(P_BLK, 2), 256, 0, stream>>>(x1, x2, part);
  colreduce_dot<<<P2_BLOCKS, 256, 0, stream>>>(part, bdot);
  final_scale<<<1, 64, 0, stream>>>(bdot, out);
}

// Round 4
// 96.741 us; speedup vs baseline: 1.1678x; 1.1678x over previous
//
#include <hip/hip_runtime.h>

// mean(x1 @ x2^T) = dot(colsum(x1), colsum(x2)) / N^2
// 3-phase atomic-free tree.
// R1: contended fp32 atomics cost ~60us -> deterministic partials.
// R2/R3: harness reset floor ~75us (256MiB ws poison fill 41us + input
//   restores ~20us). R3 (4 blk/CU, P_BLK=512) regressed: phase-1 MLP was
//   never the limit (24KB/CU in flight > 9KB needed); phase-2's serial
//   dependent-load chain grew 16->64 steps. R4: P_BLK=256 (2 blk/CU),
//   phase-2 with 4 independent fp64 accumulators (chain depth 8).

#define N_ROWS 8192
#define D_COLS 1024
#define P_BLK 256                 // partial blocks per input (2 blk/CU total)
#define RPB (N_ROWS / P_BLK)      // 32 rows per block
#define P2_BLOCKS 32              // phase-2 blocks (32 columns each)

// d_ws layout: [2][P_BLK][D_COLS] float partials (2 MiB), then [P2_BLOCKS] double.

__global__ __launch_bounds__(256) void colsum_partial(
    const float* __restrict__ x1, const float* __restrict__ x2,
    float* __restrict__ part) {
  const int bid = blockIdx.x;          // 0..511, interleave inputs via parity
  const int in = bid & 1;
  const int rb = bid >> 1;             // row-block 0..255
  const float* x = in ? x2 : x1;
  const int tid = threadIdx.x;         // owns columns [4*tid, 4*tid+4)
  const float4* xr =
      (const float4*)x + (size_t)rb * RPB * (D_COLS / 4) + tid;
  // 4 independent accumulators for load/add ILP.
  float4 a0 = make_float4(0.f, 0.f, 0.f, 0.f);
  float4 a1 = make_float4(0.f, 0.f, 0.f, 0.f);
  float4 a2 = make_float4(0.f, 0.f, 0.f, 0.f);
  float4 a3 = make_float4(0.f, 0.f, 0.f, 0.f);
#pragma unroll
  for (int r = 0; r < RPB; r += 4) {
    float4 v0 = xr[(size_t)(r + 0) * (D_COLS / 4)];
    float4 v1 = xr[(size_t)(r + 1) * (D_COLS / 4)];
    float4 v2 = xr[(size_t)(r + 2) * (D_COLS / 4)];
    float4 v3 = xr[(size_t)(r + 3) * (D_COLS / 4)];
    a0.x += v0.x; a0.y += v0.y; a0.z += v0.z; a0.w += v0.w;
    a1.x += v1.x; a1.y += v1.y; a1.z += v1.z; a1.w += v1.w;
    a2.x += v2.x; a2.y += v2.y; a2.z += v2.z; a2.w += v2.w;
    a3.x += v3.x; a3.y += v3.y; a3.z += v3.z; a3.w += v3.w;
  }
  a0.x += a1.x + a2.x + a3.x;
  a0.y += a1.y + a2.y + a3.y;
  a0.z += a1.z + a2.z + a3.z;
  a0.w += a1.w + a2.w + a3.w;
  float4* dst =
      (float4*)(part + ((size_t)in * P_BLK + rb) * D_COLS) + tid;
  *dst = a0;  // coalesced 4 KiB per block, no atomics
}

__global__ __launch_bounds__(256) void colreduce_dot(
    const float* __restrict__ part, double* __restrict__ bdot) {
  __shared__ double sh1[256], sh2[256];
  const int t = threadIdx.x;
  const int cl = t & 31;        // column within this block's 32-column chunk
  const int g = t >> 5;         // partial-group 0..7
  const int c = blockIdx.x * 32 + cl;
  const float* p1 = part + c;
  const float* p2 = part + (size_t)P_BLK * D_COLS + c;
  // 32 p-values per thread (p = g, g+8, ..): 4 independent accumulators
  // -> dependent-load chain depth 8 (R3 lesson: chain depth dominated).
  double s1a = 0.0, s1b = 0.0, s1c = 0.0, s1d = 0.0;
  double s2a = 0.0, s2b = 0.0, s2c = 0.0, s2d = 0.0;
#pragma unroll
  for (int i = 0; i < P_BLK / 8; i += 4) {
    const size_t o0 = (size_t)(g + (i + 0) * 8) * D_COLS;
    const size_t o1 = (size_t)(g + (i + 1) * 8) * D_COLS;
    const size_t o2 = (size_t)(g + (i + 2) * 8) * D_COLS;
    const size_t o3 = (size_t)(g + (i + 3) * 8) * D_COLS;
    s1a += (double)p1[o0]; s1b += (double)p1[o1];
    s1c += (double)p1[o2]; s1d += (double)p1[o3];
    s2a += (double)p2[o0]; s2b += (double)p2[o1];
    s2c += (double)p2[o2]; s2d += (double)p2[o3];
  }
  sh1[t] = (s1a + s1b) + (s1c + s1d);
  sh2[t] = (s2a + s2b) + (s2c + s2d);
  __syncthreads();
  if (t < 64) {
    double prod = 0.0;
    if (t < 32) {
      double a = 0.0, b = 0.0;
#pragma unroll
      for (int gg = 0; gg < 8; ++gg) {
        a += sh1[gg * 32 + t];
        b += sh2[gg * 32 + t];
      }
      prod = a * b;  // s1[c] * s2[c]
    }
#pragma unroll
    for (int off = 32; off > 0; off >>= 1) prod += __shfl_down(prod, off, 64);
    if (t == 0) bdot[blockIdx.x] = prod;
  }
}

__global__ __launch_bounds__(64) void final_scale(
    const double* __restrict__ bdot, float* __restrict__ out) {
  const int t = threadIdx.x;
  double s = (t < P2_BLOCKS) ? bdot[t] : 0.0;
#pragma unroll
  for (int off = 32; off > 0; off >>= 1) s += __shfl_down(s, off, 64);
  if (t == 0) out[0] = (float)(s / ((double)N_ROWS * (double)N_ROWS));
}

extern "C" void kernel_launch(void* const* d_in, const int* in_sizes, int n_in,
                              void* d_out, int out_size, void* d_ws,
                              size_t ws_size, hipStream_t stream) {
  const float* x1 = (const float*)d_in[0];
  const float* x2 = (const float*)d_in[1];
  float* part = (float*)d_ws;  // 2 * 256 * 1024 floats = 2 MiB
  double* bdot =
      (double*)((char*)d_ws + (size_t)2 * P_BLK * D_COLS * sizeof(float));
  float* out = (float*)d_out;

  colsum_partial<<<2 * P_BLK, 256, 0, stream>>>(x1, x2, part);
  colreduce_dot<<<P2_BLOCKS, 256, 0, stream>>>(part, bdot);
  final_scale<<<1, 64, 0, stream>>>(bdot, out);
}

// Round 5
// 95.672 us; speedup vs baseline: 1.1809x; 1.0112x over previous
//
#include <hip/hip_runtime.h>

// mean(x1 @ x2^T) = dot(colsum(x1), colsum(x2)) / N^2
// Two launches:
//   P1: per-block partial column sums -> d_ws (BW-bound, 64 MiB read)
//       + zeroes the P2 control block (kernel-boundary ordering).
//   P2: 32 blocks reduce partials per column, dot s1*s2, f64 atomicAdd into
//       a global accumulator; last-ticket block writes the scalar.
// History: R1 1M contended fp32 atomics ~60us -> deterministic partials.
//   R2/R3: harness reset floor ~75us (256MiB ws poison fill + restores);
//   R3's P_BLK=512 regressed phase-2 chain depth. R4: P_BLK=256, 4-way f64
//   ILP in phase 2 -> 96.7us. R5: fuse phase 3 into phase 2 (3->2 launches).

#define N_ROWS 8192
#define D_COLS 1024
#define P_BLK 256                 // partial blocks per input (2 blk/CU total)
#define RPB (N_ROWS / P_BLK)      // 32 rows per block
#define P2_BLOCKS 32              // phase-2 blocks (32 columns each)

// d_ws layout: [2][P_BLK][D_COLS] float partials (2 MiB),
// then control block: { double acc; unsigned counter; }.

struct Ctrl {
  double acc;
  unsigned counter;
};

__global__ __launch_bounds__(256) void colsum_partial(
    const float* __restrict__ x1, const float* __restrict__ x2,
    float* __restrict__ part, Ctrl* __restrict__ ctrl) {
  if (blockIdx.x == 0 && threadIdx.x == 0) {
    ctrl->acc = 0.0;      // visible to phase 2 via kernel-boundary ordering
    ctrl->counter = 0u;
  }
  const int bid = blockIdx.x;          // 0..511, interleave inputs via parity
  const int in = bid & 1;
  const int rb = bid >> 1;             // row-block 0..255
  const float* x = in ? x2 : x1;
  const int tid = threadIdx.x;         // owns columns [4*tid, 4*tid+4)
  const float4* xr =
      (const float4*)x + (size_t)rb * RPB * (D_COLS / 4) + tid;
  // 4 independent accumulators for load/add ILP.
  float4 a0 = make_float4(0.f, 0.f, 0.f, 0.f);
  float4 a1 = make_float4(0.f, 0.f, 0.f, 0.f);
  float4 a2 = make_float4(0.f, 0.f, 0.f, 0.f);
  float4 a3 = make_float4(0.f, 0.f, 0.f, 0.f);
#pragma unroll
  for (int r = 0; r < RPB; r += 4) {
    float4 v0 = xr[(size_t)(r + 0) * (D_COLS / 4)];
    float4 v1 = xr[(size_t)(r + 1) * (D_COLS / 4)];
    float4 v2 = xr[(size_t)(r + 2) * (D_COLS / 4)];
    float4 v3 = xr[(size_t)(r + 3) * (D_COLS / 4)];
    a0.x += v0.x; a0.y += v0.y; a0.z += v0.z; a0.w += v0.w;
    a1.x += v1.x; a1.y += v1.y; a1.z += v1.z; a1.w += v1.w;
    a2.x += v2.x; a2.y += v2.y; a2.z += v2.z; a2.w += v2.w;
    a3.x += v3.x; a3.y += v3.y; a3.z += v3.z; a3.w += v3.w;
  }
  a0.x += a1.x + a2.x + a3.x;
  a0.y += a1.y + a2.y + a3.y;
  a0.z += a1.z + a2.z + a3.z;
  a0.w += a1.w + a2.w + a3.w;
  float4* dst =
      (float4*)(part + ((size_t)in * P_BLK + rb) * D_COLS) + tid;
  *dst = a0;  // coalesced 4 KiB per block, no atomics
}

__global__ __launch_bounds__(256) void colreduce_dot_final(
    const float* __restrict__ part, Ctrl* __restrict__ ctrl,
    float* __restrict__ out) {
  __shared__ double sh1[256], sh2[256];
  const int t = threadIdx.x;
  const int cl = t & 31;        // column within this block's 32-column chunk
  const int g = t >> 5;         // partial-group 0..7
  const int c = blockIdx.x * 32 + cl;
  const float* p1 = part + c;
  const float* p2 = part + (size_t)P_BLK * D_COLS + c;
  // 32 p-values per thread: 4 independent f64 accumulators (chain depth 8).
  double s1a = 0.0, s1b = 0.0, s1c = 0.0, s1d = 0.0;
  double s2a = 0.0, s2b = 0.0, s2c = 0.0, s2d = 0.0;
#pragma unroll
  for (int i = 0; i < P_BLK / 8; i += 4) {
    const size_t o0 = (size_t)(g + (i + 0) * 8) * D_COLS;
    const size_t o1 = (size_t)(g + (i + 1) * 8) * D_COLS;
    const size_t o2 = (size_t)(g + (i + 2) * 8) * D_COLS;
    const size_t o3 = (size_t)(g + (i + 3) * 8) * D_COLS;
    s1a += (double)p1[o0]; s1b += (double)p1[o1];
    s1c += (double)p1[o2]; s1d += (double)p1[o3];
    s2a += (double)p2[o0]; s2b += (double)p2[o1];
    s2c += (double)p2[o2]; s2d += (double)p2[o3];
  }
  sh1[t] = (s1a + s1b) + (s1c + s1d);
  sh2[t] = (s2a + s2b) + (s2c + s2d);
  __syncthreads();
  if (t < 64) {
    double prod = 0.0;
    if (t < 32) {
      double a = 0.0, b = 0.0;
#pragma unroll
      for (int gg = 0; gg < 8; ++gg) {
        a += sh1[gg * 32 + t];
        b += sh2[gg * 32 + t];
      }
      prod = a * b;  // s1[c] * s2[c]
    }
#pragma unroll
    for (int off = 32; off > 0; off >>= 1) prod += __shfl_down(prod, off, 64);
    if (t == 0) {
      // 32 uncontended device-scope f64 atomics (R1 lesson: contention, not
      // atomics per se, was the killer).
      __hip_atomic_fetch_add(&ctrl->acc, prod, __ATOMIC_RELAXED,
                             __HIP_MEMORY_SCOPE_AGENT);
      unsigned old = __hip_atomic_fetch_add(&ctrl->counter, 1u,
                                            __ATOMIC_ACQ_REL,
                                            __HIP_MEMORY_SCOPE_AGENT);
      if (old == P2_BLOCKS - 1) {  // last block: total is complete
        double total = __hip_atomic_load(&ctrl->acc, __ATOMIC_ACQUIRE,
                                         __HIP_MEMORY_SCOPE_AGENT);
        out[0] = (float)(total / ((double)N_ROWS * (double)N_ROWS));
      }
    }
  }
}

extern "C" void kernel_launch(void* const* d_in, const int* in_sizes, int n_in,
                              void* d_out, int out_size, void* d_ws,
                              size_t ws_size, hipStream_t stream) {
  const float* x1 = (const float*)d_in[0];
  const float* x2 = (const float*)d_in[1];
  float* part = (float*)d_ws;  // 2 * 256 * 1024 floats = 2 MiB
  Ctrl* ctrl =
      (Ctrl*)((char*)d_ws + (size_t)2 * P_BLK * D_COLS * sizeof(float));
  float* out = (float*)d_out;

  colsum_partial<<<2 * P_BLK, 256, 0, stream>>>(x1, x2, part, ctrl);
  colreduce_dot_final<<<P2_BLOCKS, 256, 0, stream>>>(part, ctrl, out);
}